// Round 1
// baseline (2000.512 us; speedup 1.0000x reference)
//
#include <hip/hip_runtime.h>
#include <math.h>

#define Ttok 512
#define Hd   1024
#define Ne   64
#define Ir   512
#define Ngrp 8
#define TGn  3
#define Kn   6
#define I2d  1024

__device__ __forceinline__ float wred64(float v) {
  #pragma unroll
  for (int m = 32; m >= 1; m >>= 1) v += __shfl_xor(v, m, 64);
  return v;
}

// One block (1 wave, 64 threads) per token: scores, group top-3, top-6 experts,
// normalized weights, scatter into per-expert token lists.
__global__ __launch_bounds__(64) void router_kernel(
    const float* __restrict__ x, const float* __restrict__ gate,
    int* __restrict__ cnt, int* __restrict__ tok, float* __restrict__ wtl)
{
  const int t = blockIdx.x;
  const int lane = threadIdx.x;
  __shared__ float xs[Hd];
  __shared__ float sc[Ne];
  #pragma unroll
  for (int j = 0; j < Hd / 64; ++j) xs[lane + 64 * j] = x[(size_t)t * Hd + lane + 64 * j];
  __syncthreads();
  for (int e = 0; e < Ne; ++e) {
    const float* gr = gate + (size_t)e * Hd;
    float p = 0.f;
    #pragma unroll
    for (int j = 0; j < Hd / 64; ++j) p = fmaf(gr[lane + 64 * j], xs[lane + 64 * j], p);
    p = wred64(p);
    if (lane == 0) sc[e] = 1.f / (1.f + expf(-p));
  }
  __syncthreads();
  if (lane == 0) {
    float gs[Ngrp];
    #pragma unroll
    for (int g = 0; g < Ngrp; ++g) {
      float m = sc[g * 8];
      #pragma unroll
      for (int j = 1; j < 8; ++j) m = fmaxf(m, sc[g * 8 + j]);
      gs[g] = m;
    }
    unsigned gsel = 0;
    for (int r = 0; r < TGn; ++r) {
      int bg = -1; float bv = -3.4e38f;
      for (int g = 0; g < Ngrp; ++g)
        if (!((gsel >> g) & 1u) && gs[g] > bv) { bv = gs[g]; bg = g; }
      gsel |= 1u << bg;
    }
    int ide[Kn]; float val[Kn];
    unsigned long long taken = 0ull;
    for (int k = 0; k < Kn; ++k) {
      int be = -1; float bv = -3.4e38f;
      for (int e = 0; e < Ne; ++e) {
        if (!((gsel >> (e >> 3)) & 1u)) continue;
        if ((taken >> e) & 1ull) continue;
        if (sc[e] > bv) { bv = sc[e]; be = e; }
      }
      taken |= 1ull << be;
      ide[k] = be; val[k] = bv;
    }
    float s = 0.f;
    for (int k = 0; k < Kn; ++k) s += val[k];
    s += 1e-20f;
    for (int k = 0; k < Kn; ++k) {
      float w = val[k] / s * 2.5f;
      int e = ide[k];
      int slot = atomicAdd(&cnt[e], 1);
      tok[e * Ttok + slot] = t;
      wtl[e * Ttok + slot] = w;
    }
  }
}

__global__ void offs_kernel(const int* __restrict__ cnt, int* __restrict__ offs) {
  if (threadIdx.x == 0 && blockIdx.x == 0) {
    int a = 0;
    for (int e = 0; e < Ne; ++e) { offs[e] = a; a += cnt[e]; }
    offs[Ne] = a;
  }
}

// Gate+Up: block = 256 thr (4 waves). Each wave owns 8 weight rows (2 batches of 4),
// dequants them into regs (read-once, coalesced), then loops tokens: dot + wave
// reduce, silu(g)*u, float4 store into hmid.
// Generalized: routed (toks/cnt/offs set) or shared (null -> identity tokens, e=0).
__global__ __launch_bounds__(256) void gu_kernel(
    const float* __restrict__ x,
    const int* __restrict__ wgq, const float* __restrict__ sg,
    const int* __restrict__ wuq, const float* __restrict__ su,
    const int* __restrict__ toks, const int* __restrict__ cnt,
    const int* __restrict__ offs, float* __restrict__ hmid,
    int Idim, int tokPerChunk)
{
  const int e = blockIdx.y;
  const int n = cnt ? cnt[e] : Ttok;
  const int t0 = blockIdx.z * tokPerChunk;
  const int t1 = min(t0 + tokPerChunk, n);
  if (t0 >= t1) return;
  const int rbase = offs ? offs[e] : 0;
  const int wave = threadIdx.x >> 6;
  const int lane = threadIdx.x & 63;
  const int sRows = Idim >> 7;
  #pragma unroll 1
  for (int batch = 0; batch < 2; ++batch) {
    const int r0 = blockIdx.x * 32 + wave * 8 + batch * 4;
    float wgv[4][16], wuv[4][16];
    #pragma unroll
    for (int rr = 0; rr < 4; ++rr) {
      const int row = r0 + rr;
      const int* pg = wgq + ((size_t)e * Idim + row) * Hd;
      const int* pu = wuq + ((size_t)e * Idim + row) * Hd;
      const float* sgr = sg + ((size_t)e * sRows + (row >> 7)) * 8;
      const float* sur = su + ((size_t)e * sRows + (row >> 7)) * 8;
      #pragma unroll
      for (int j = 0; j < 16; ++j) {
        const int h = lane + 64 * j;
        wgv[rr][j] = (float)pg[h] * sgr[h >> 7];
        wuv[rr][j] = (float)pu[h] * sur[h >> 7];
      }
    }
    #pragma unroll 1
    for (int sI = t0; sI < t1; ++sI) {
      const int t = toks ? toks[e * Ttok + sI] : sI;
      const float* xr = x + (size_t)t * Hd;
      float xv[16];
      #pragma unroll
      for (int j = 0; j < 16; ++j) xv[j] = xr[lane + 64 * j];
      float red[8];
      #pragma unroll
      for (int rr = 0; rr < 4; ++rr) {
        float ag = 0.f, au = 0.f;
        #pragma unroll
        for (int j = 0; j < 16; ++j) {
          ag = fmaf(wgv[rr][j], xv[j], ag);
          au = fmaf(wuv[rr][j], xv[j], au);
        }
        red[rr * 2]     = wred64(ag);
        red[rr * 2 + 1] = wred64(au);
      }
      if (lane == 0) {
        float4 o;
        float* op = (float*)&o;
        #pragma unroll
        for (int rr = 0; rr < 4; ++rr) {
          float g = red[rr * 2], u = red[rr * 2 + 1];
          op[rr] = g / (1.f + expf(-g)) * u;
        }
        *(float4*)&hmid[(size_t)(rbase + sI) * Idim + r0] = o;
      }
    }
  }
}

// Down: block 256 thr, each thread one output column h. Token batch of 32 rows in
// regs; stream weights coalesced across lanes; atomicAdd (x routing weight) into out.
__global__ __launch_bounds__(256) void down_kernel(
    const float* __restrict__ hmid,
    const int* __restrict__ wdq, const float* __restrict__ sd,
    const int* __restrict__ toks, const float* __restrict__ wtl,
    const int* __restrict__ cnt, const int* __restrict__ offs,
    float* __restrict__ out, int Idim, int nIchunks)
{
  const int e = blockIdx.y;
  const int n = cnt ? cnt[e] : Ttok;
  const int ic = blockIdx.z % nIchunks;
  const int b  = blockIdx.z / nIchunks;
  const int s0 = b * 32;
  if (s0 >= n) return;
  const int ns = min(32, n - s0);
  const int rbase = offs ? offs[e] : 0;
  const int h = blockIdx.x * 256 + threadIdx.x;
  const int sRows = Idim >> 7;
  const int iLen = Idim / nIchunks;
  const int i0 = ic * iLen;
  float acc[32];
  #pragma unroll
  for (int r = 0; r < 32; ++r) acc[r] = 0.f;
  const int* wp = wdq + (size_t)e * Idim * Hd + h;
  const float* hbase = hmid + (size_t)(rbase + s0) * Idim;
  if (ns == 32) {
    for (int ib = i0; ib < i0 + iLen; ib += 128) {
      const float scv = sd[((size_t)e * sRows + (ib >> 7)) * 8 + (h >> 7)];
      #pragma unroll 4
      for (int ii = 0; ii < 128; ++ii) {
        const int i = ib + ii;
        const float w = (float)wp[(size_t)i * Hd] * scv;
        const float* hp = hbase + i;
        #pragma unroll
        for (int r = 0; r < 32; ++r)
          acc[r] = fmaf(hp[(size_t)r * Idim], w, acc[r]);
      }
    }
  } else {
    for (int ib = i0; ib < i0 + iLen; ib += 128) {
      const float scv = sd[((size_t)e * sRows + (ib >> 7)) * 8 + (h >> 7)];
      #pragma unroll 4
      for (int ii = 0; ii < 128; ++ii) {
        const int i = ib + ii;
        const float w = (float)wp[(size_t)i * Hd] * scv;
        const float* hp = hbase + i;
        #pragma unroll
        for (int r = 0; r < 32; ++r)
          if (r < ns) acc[r] = fmaf(hp[(size_t)r * Idim], w, acc[r]);
      }
    }
  }
  for (int r = 0; r < ns; ++r) {
    const int t = toks ? toks[e * Ttok + s0 + r] : (s0 + r);
    const float wt = wtl ? wtl[e * Ttok + s0 + r] : 1.f;
    atomicAdd(&out[(size_t)t * Hd + h], wt * acc[r]);
  }
}

extern "C" void kernel_launch(void* const* d_in, const int* in_sizes, int n_in,
                              void* d_out, int out_size, void* d_ws, size_t ws_size,
                              hipStream_t stream)
{
  const float* x    = (const float*)d_in[0];
  const float* gate = (const float*)d_in[1];
  const int*   wg   = (const int*)d_in[2];
  const float* sg   = (const float*)d_in[3];
  const int*   wu   = (const int*)d_in[4];
  const float* su   = (const float*)d_in[5];
  const int*   wd   = (const int*)d_in[6];
  const float* sd   = (const float*)d_in[7];
  const int*   shwg = (const int*)d_in[8];
  const float* shsg = (const float*)d_in[9];
  const int*   shwu = (const int*)d_in[10];
  const float* shsu = (const float*)d_in[11];
  const int*   shwd = (const int*)d_in[12];
  const float* shsd = (const float*)d_in[13];
  float* out = (float*)d_out;

  char* ws = (char*)d_ws;
  int*   cnt    = (int*)(ws);                    // 64 ints
  int*   offs   = (int*)(ws + 1024);             // 65 ints
  int*   tok    = (int*)(ws + 4096);             // 64*512 ints
  float* wtl    = (float*)(ws + 4096 + 131072);  // 64*512 floats
  float* hmid_r = (float*)(ws + (size_t)(1 << 20));        // 3072*512 f32 = 6 MB
  float* hmid_s = (float*)(ws + (size_t)(8 << 20));        // 512*1024 f32 = 2 MB

  hipMemsetAsync(cnt, 0, Ne * sizeof(int), stream);
  hipMemsetAsync(out, 0, (size_t)out_size * sizeof(float), stream);

  router_kernel<<<Ttok, 64, 0, stream>>>(x, gate, cnt, tok, wtl);
  offs_kernel<<<1, 64, 0, stream>>>(cnt, offs);

  // routed gate/up: grid (I/32, E, 1); one token chunk covers worst case n_e=512
  gu_kernel<<<dim3(Ir / 32, Ne, 1), 256, 0, stream>>>(
      x, wg, sg, wu, su, tok, cnt, offs, hmid_r, Ir, Ttok);
  // shared gate/up: e=0, identity tokens, 8 chunks of 64 tokens
  gu_kernel<<<dim3(I2d / 32, 1, 8), 256, 0, stream>>>(
      x, shwg, shsg, shwu, shsu, nullptr, nullptr, nullptr, hmid_s, I2d, 64);

  // routed down: grid (H/256, E, max 16 token batches), no i-split
  down_kernel<<<dim3(4, Ne, 16), 256, 0, stream>>>(
      hmid_r, wd, sd, tok, wtl, cnt, offs, out, Ir, 1);
  // shared down: 16 token batches x 4 i-chunks
  down_kernel<<<dim3(4, 1, 64), 256, 0, stream>>>(
      hmid_s, shwd, shsd, nullptr, nullptr, nullptr, nullptr, out, I2d, 4);
}

// Round 2
// 770.271 us; speedup vs baseline: 2.5972x; 2.5972x over previous
//
#include <hip/hip_runtime.h>
#include <math.h>

#define Ttok 512
#define Hd   1024
#define Ne   64
#define Ir   512
#define I2d  1024
#define Kn   6
#define Ngrp 8
#define TGn  3

typedef __bf16 bf16x8 __attribute__((ext_vector_type(8)));
typedef float f32x4 __attribute__((ext_vector_type(4)));
typedef unsigned short u16x8 __attribute__((ext_vector_type(8)));

__device__ __forceinline__ unsigned short f2bf(float f) {
  unsigned u = __builtin_bit_cast(unsigned, f);
  return (unsigned short)((u + 0x7fffu + ((u >> 16) & 1u)) >> 16);
}
__device__ __forceinline__ float bf2f(unsigned short h) {
  unsigned u = ((unsigned)h) << 16;
  return __builtin_bit_cast(float, u);
}

__device__ __forceinline__ float wred64(float v) {
  #pragma unroll
  for (int m = 32; m >= 1; m >>= 1) v += __shfl_xor(v, m, 64);
  return v;
}

// ---------- router: 1 wave per token ----------
__global__ __launch_bounds__(64) void router_kernel(
    const float* __restrict__ x, const float* __restrict__ gate,
    int* __restrict__ cnt, int* __restrict__ tok,
    int* __restrict__ eidloc, float* __restrict__ wtk)
{
  const int t = blockIdx.x;
  const int lane = threadIdx.x;
  __shared__ float xs[Hd];
  __shared__ float sc[Ne];
  #pragma unroll
  for (int j = 0; j < Hd / 64; ++j) xs[lane + 64 * j] = x[(size_t)t * Hd + lane + 64 * j];
  __syncthreads();
  for (int e = 0; e < Ne; ++e) {
    const float* gr = gate + (size_t)e * Hd;
    float p = 0.f;
    #pragma unroll
    for (int j = 0; j < Hd / 64; ++j) p = fmaf(gr[lane + 64 * j], xs[lane + 64 * j], p);
    p = wred64(p);
    if (lane == 0) sc[e] = 1.f / (1.f + expf(-p));
  }
  __syncthreads();
  if (lane == 0) {
    float gs[Ngrp];
    #pragma unroll
    for (int g = 0; g < Ngrp; ++g) {
      float m = sc[g * 8];
      #pragma unroll
      for (int j = 1; j < 8; ++j) m = fmaxf(m, sc[g * 8 + j]);
      gs[g] = m;
    }
    unsigned gsel = 0;
    for (int r = 0; r < TGn; ++r) {
      int bg = -1; float bv = -3.4e38f;
      for (int g = 0; g < Ngrp; ++g)
        if (!((gsel >> g) & 1u) && gs[g] > bv) { bv = gs[g]; bg = g; }
      gsel |= 1u << bg;
    }
    int ide[Kn]; float val[Kn];
    unsigned long long taken = 0ull;
    for (int k = 0; k < Kn; ++k) {
      int be = -1; float bv = -3.4e38f;
      for (int e = 0; e < Ne; ++e) {
        if (!((gsel >> (e >> 3)) & 1u)) continue;
        if ((taken >> e) & 1ull) continue;
        if (sc[e] > bv) { bv = sc[e]; be = e; }
      }
      taken |= 1ull << be;
      ide[k] = be; val[k] = bv;
    }
    float s = 0.f;
    for (int k = 0; k < Kn; ++k) s += val[k];
    s += 1e-20f;
    for (int k = 0; k < Kn; ++k) {
      float w = val[k] / s * 2.5f;
      int e = ide[k];
      int slot = atomicAdd(&cnt[e], 1);
      tok[e * Ttok + slot] = t;
      eidloc[t * Kn + k] = (e << 16) | slot;
      wtk[t * Kn + k] = w;
    }
  }
}

__global__ void offs_kernel(const int* __restrict__ cnt, int* __restrict__ offs) {
  if (threadIdx.x == 0 && blockIdx.x == 0) {
    int a = 0;
    for (int e = 0; e < Ne; ++e) { offs[e] = a; a += cnt[e]; }
    offs[Ne] = a;
  }
}

// ---------- hi/lo bf16 split of x: identity rows [0,512) ----------
__global__ __launch_bounds__(256) void split_x(
    const float* __restrict__ x, unsigned short* __restrict__ xh, unsigned short* __restrict__ xl)
{
  const int r = blockIdx.x * 4 + (threadIdx.x >> 6);
  const int lane = threadIdx.x & 63;
  const float* px = x + (size_t)r * Hd;
  #pragma unroll
  for (int j = 0; j < Hd / 64; ++j) {
    float f = px[lane + 64 * j];
    unsigned short hh = f2bf(f);
    unsigned short hl = f2bf(f - bf2f(hh));
    xh[(size_t)r * Hd + lane + 64 * j] = hh;
    xl[(size_t)r * Hd + lane + 64 * j] = hl;
  }
}

// ---------- gathered rows [512, 512+3072): per-expert compact token rows ----------
__global__ __launch_bounds__(256) void gather_x(
    const float* __restrict__ x, const int* __restrict__ tok,
    const int* __restrict__ cnt, const int* __restrict__ offs,
    unsigned short* __restrict__ xh, unsigned short* __restrict__ xl)
{
  const int e = blockIdx.x;
  const int n = cnt[e];
  const int chunk = blockIdx.y;
  const int wave = threadIdx.x >> 6;
  const int lane = threadIdx.x & 63;
  for (int it = 0; it < 16; ++it) {
    const int s = chunk * 64 + it * 4 + wave;
    if (s >= n) break;
    const int t = tok[e * Ttok + s];
    const int row = 512 + offs[e] + s;
    const float* px = x + (size_t)t * Hd;
    #pragma unroll
    for (int j = 0; j < Hd / 64; ++j) {
      float f = px[lane + 64 * j];
      unsigned short hh = f2bf(f);
      unsigned short hl = f2bf(f - bf2f(hh));
      xh[(size_t)row * Hd + lane + 64 * j] = hh;
      xl[(size_t)row * Hd + lane + 64 * j] = hl;
    }
  }
}

// ---------- gate+up MFMA GEMM ----------
// C[slot, i] = sum_h X[slot,h]*W[i,h]; block = 64 M-rows x 64 i-cols (4 waves, 16-i strip each)
__global__ __launch_bounds__(256) void gu_mfma(
    const unsigned short* __restrict__ xh, const unsigned short* __restrict__ xl,
    const int* __restrict__ wgq, const float* __restrict__ sgs,
    const int* __restrict__ wuq, const float* __restrict__ sus,
    const int* __restrict__ cnt, const int* __restrict__ offs,
    unsigned short* __restrict__ hmh, unsigned short* __restrict__ hml,
    int Idim)
{
  const int e = blockIdx.y;
  const int n = cnt ? cnt[e] : Ttok;
  const int mbase = blockIdx.z * 64;
  if (mbase >= n) return;
  const int xbase = offs ? (512 + offs[e]) : 0;
  const int hbase = offs ? offs[e] : 0;
  const int lane = threadIdx.x & 63;
  const int wave = threadIdx.x >> 6;
  const int i0 = blockIdx.x * 64;
  const int iW = i0 + wave * 16 + (lane & 15);
  const int qk = lane >> 4;

  const int* pG = wgq + ((size_t)e * Idim + iW) * Hd;
  const int* pU = wuq + ((size_t)e * Idim + iW) * Hd;
  const int sRow = Idim >> 7;
  const float* sG0 = sgs + ((size_t)e * sRow + (i0 >> 7)) * 8;
  const float* sU0 = sus + ((size_t)e * sRow + (i0 >> 7)) * 8;
  const unsigned short* pXh = xh + (size_t)(xbase + mbase) * Hd;
  const unsigned short* pXl = xl + (size_t)(xbase + mbase) * Hd;

  const f32x4 z4 = {0.f, 0.f, 0.f, 0.f};
  f32x4 aG[4], aU[4];
  #pragma unroll
  for (int m = 0; m < 4; ++m) { aG[m] = z4; aU[m] = z4; }

  #pragma unroll 1
  for (int kb = 0; kb < 8; ++kb) {
    f32x4 pGa[4], pUa[4];
    #pragma unroll
    for (int m = 0; m < 4; ++m) { pGa[m] = z4; pUa[m] = z4; }
    #pragma unroll
    for (int ks = 0; ks < 4; ++ks) {
      const int k0 = kb * 128 + ks * 32 + qk * 8;
      int4 g0 = *(const int4*)(pG + k0);
      int4 g1 = *(const int4*)(pG + k0 + 4);
      int4 u0 = *(const int4*)(pU + k0);
      int4 u1 = *(const int4*)(pU + k0 + 4);
      union { bf16x8 v; unsigned short s[8]; } bg, bu;
      bg.s[0] = f2bf((float)g0.x); bg.s[1] = f2bf((float)g0.y);
      bg.s[2] = f2bf((float)g0.z); bg.s[3] = f2bf((float)g0.w);
      bg.s[4] = f2bf((float)g1.x); bg.s[5] = f2bf((float)g1.y);
      bg.s[6] = f2bf((float)g1.z); bg.s[7] = f2bf((float)g1.w);
      bu.s[0] = f2bf((float)u0.x); bu.s[1] = f2bf((float)u0.y);
      bu.s[2] = f2bf((float)u0.z); bu.s[3] = f2bf((float)u0.w);
      bu.s[4] = f2bf((float)u1.x); bu.s[5] = f2bf((float)u1.y);
      bu.s[6] = f2bf((float)u1.z); bu.s[7] = f2bf((float)u1.w);
      #pragma unroll
      for (int m = 0; m < 4; ++m) {
        const size_t aoff = (size_t)(m * 16 + (lane & 15)) * Hd + k0;
        bf16x8 ahv = __builtin_bit_cast(bf16x8, *(const u16x8*)(pXh + aoff));
        bf16x8 alv = __builtin_bit_cast(bf16x8, *(const u16x8*)(pXl + aoff));
        pGa[m] = __builtin_amdgcn_mfma_f32_16x16x32_bf16(ahv, bg.v, pGa[m], 0, 0, 0);
        pGa[m] = __builtin_amdgcn_mfma_f32_16x16x32_bf16(alv, bg.v, pGa[m], 0, 0, 0);
        pUa[m] = __builtin_amdgcn_mfma_f32_16x16x32_bf16(ahv, bu.v, pUa[m], 0, 0, 0);
        pUa[m] = __builtin_amdgcn_mfma_f32_16x16x32_bf16(alv, bu.v, pUa[m], 0, 0, 0);
      }
    }
    const float sg = sG0[kb], su = sU0[kb];
    #pragma unroll
    for (int m = 0; m < 4; ++m) { aG[m] += sg * pGa[m]; aU[m] += su * pUa[m]; }
  }

  #pragma unroll
  for (int m = 0; m < 4; ++m) {
    #pragma unroll
    for (int j = 0; j < 4; ++j) {
      const int mr = mbase + m * 16 + qk * 4 + j;
      if (mr < n) {
        float g = aG[m][j], u = aU[m][j];
        float hv = g / (1.f + expf(-g)) * u;
        unsigned short hh = f2bf(hv);
        unsigned short hl = f2bf(hv - bf2f(hh));
        const size_t off = (size_t)(hbase + mr) * Idim + iW;
        hmh[off] = hh;
        hml[off] = hl;
      }
    }
  }
}

// ---------- down MFMA GEMM ----------
// Y[slot, h] = sum_i hm[slot,i]*Wd[i,h]; Wd row-major [K=I, H] (h contiguous)
__global__ __launch_bounds__(256) void down_mfma(
    const unsigned short* __restrict__ hmh, const unsigned short* __restrict__ hml,
    const int* __restrict__ wdq, const float* __restrict__ sds,
    const int* __restrict__ cnt, const int* __restrict__ offs,
    float* __restrict__ yout, int Kd)
{
  const int e = blockIdx.y;
  const int n = cnt ? cnt[e] : Ttok;
  const int mbase = blockIdx.z * 64;
  if (mbase >= n) return;
  const int sbase = offs ? offs[e] : 0;
  const int lane = threadIdx.x & 63;
  const int wave = threadIdx.x >> 6;
  const int h0 = blockIdx.x * 64;
  const int hW = h0 + wave * 16 + (lane & 15);
  const int qk = lane >> 4;

  const int* pW = wdq + (size_t)e * Kd * Hd + hW;
  const float* sD0 = sds + (size_t)e * (Kd >> 7) * 8 + (h0 >> 7);
  const unsigned short* pAh = hmh + (size_t)(sbase + mbase) * Kd;
  const unsigned short* pAl = hml + (size_t)(sbase + mbase) * Kd;

  const f32x4 z4 = {0.f, 0.f, 0.f, 0.f};
  f32x4 acc[4];
  #pragma unroll
  for (int m = 0; m < 4; ++m) acc[m] = z4;

  const int nKb = Kd >> 7;
  #pragma unroll 1
  for (int kb = 0; kb < nKb; ++kb) {
    f32x4 pa[4];
    #pragma unroll
    for (int m = 0; m < 4; ++m) pa[m] = z4;
    #pragma unroll
    for (int ks = 0; ks < 4; ++ks) {
      const int k0 = kb * 128 + ks * 32 + qk * 8;
      union { bf16x8 v; unsigned short s[8]; } bw;
      #pragma unroll
      for (int j = 0; j < 8; ++j)
        bw.s[j] = f2bf((float)pW[(size_t)(k0 + j) * Hd]);
      #pragma unroll
      for (int m = 0; m < 4; ++m) {
        const size_t aoff = (size_t)(m * 16 + (lane & 15)) * Kd + k0;
        bf16x8 ahv = __builtin_bit_cast(bf16x8, *(const u16x8*)(pAh + aoff));
        bf16x8 alv = __builtin_bit_cast(bf16x8, *(const u16x8*)(pAl + aoff));
        pa[m] = __builtin_amdgcn_mfma_f32_16x16x32_bf16(ahv, bw.v, pa[m], 0, 0, 0);
        pa[m] = __builtin_amdgcn_mfma_f32_16x16x32_bf16(alv, bw.v, pa[m], 0, 0, 0);
      }
    }
    const float sc = sD0[kb * 8];
    #pragma unroll
    for (int m = 0; m < 4; ++m) acc[m] += sc * pa[m];
  }

  #pragma unroll
  for (int m = 0; m < 4; ++m) {
    #pragma unroll
    for (int j = 0; j < 4; ++j) {
      const int mr = mbase + m * 16 + qk * 4 + j;
      if (mr < n)
        yout[(size_t)(sbase + mr) * Hd + hW] = acc[m][j];
    }
  }
}

// ---------- final combine: out[t] = ysh[t] + sum_k w_k * yslot[row_k] ----------
__global__ __launch_bounds__(256) void combine_kernel(
    const float* __restrict__ ysh, const float* __restrict__ yslot,
    const int* __restrict__ eidloc, const float* __restrict__ wtk,
    const int* __restrict__ offs, float* __restrict__ out)
{
  const int t = blockIdx.x;
  const int c = threadIdx.x * 4;
  float4 a = *(const float4*)(ysh + (size_t)t * Hd + c);
  #pragma unroll
  for (int k = 0; k < Kn; ++k) {
    const int el = eidloc[t * Kn + k];
    const float w = wtk[t * Kn + k];
    const int row = offs[el >> 16] + (el & 0xFFFF);
    const float4 b = *(const float4*)(yslot + (size_t)row * Hd + c);
    a.x += w * b.x; a.y += w * b.y; a.z += w * b.z; a.w += w * b.w;
  }
  *(float4*)(out + (size_t)t * Hd + c) = a;
}

extern "C" void kernel_launch(void* const* d_in, const int* in_sizes, int n_in,
                              void* d_out, int out_size, void* d_ws, size_t ws_size,
                              hipStream_t stream)
{
  const float* x    = (const float*)d_in[0];
  const float* gate = (const float*)d_in[1];
  const int*   wg   = (const int*)d_in[2];
  const float* sg   = (const float*)d_in[3];
  const int*   wu   = (const int*)d_in[4];
  const float* su   = (const float*)d_in[5];
  const int*   wd   = (const int*)d_in[6];
  const float* sd   = (const float*)d_in[7];
  const int*   shwg = (const int*)d_in[8];
  const float* shsg = (const float*)d_in[9];
  const int*   shwu = (const int*)d_in[10];
  const float* shsu = (const float*)d_in[11];
  const int*   shwd = (const int*)d_in[12];
  const float* shsd = (const float*)d_in[13];
  float* out = (float*)d_out;

  char* p = (char*)d_ws;
  auto nxt = [&](size_t bytes) { char* r = p; p += (bytes + 255) & ~(size_t)255; return r; };
  int* cnt    = (int*)nxt(Ne * 4);
  int* offs   = (int*)nxt((Ne + 1) * 4);
  int* tok    = (int*)nxt((size_t)Ne * Ttok * 4);
  int* eidloc = (int*)nxt((size_t)Ttok * Kn * 4);
  float* wtk  = (float*)nxt((size_t)Ttok * Kn * 4);
  unsigned short* xgh = (unsigned short*)nxt((size_t)3648 * Hd * 2);
  unsigned short* xgl = (unsigned short*)nxt((size_t)3648 * Hd * 2);
  unsigned short* hrh = (unsigned short*)nxt((size_t)3136 * Ir * 2);
  unsigned short* hrl = (unsigned short*)nxt((size_t)3136 * Ir * 2);
  unsigned short* hsh = (unsigned short*)nxt((size_t)Ttok * I2d * 2);
  unsigned short* hsl = (unsigned short*)nxt((size_t)Ttok * I2d * 2);
  float* yslot = (float*)nxt((size_t)3136 * Hd * 4);
  float* ysh   = (float*)nxt((size_t)Ttok * Hd * 4);

  hipMemsetAsync(cnt, 0, Ne * 4, stream);
  hipMemsetAsync(xgh + (size_t)3584 * Hd, 0, (size_t)64 * Hd * 2, stream);
  hipMemsetAsync(xgl + (size_t)3584 * Hd, 0, (size_t)64 * Hd * 2, stream);
  hipMemsetAsync(hrh + (size_t)3072 * Ir, 0, (size_t)64 * Ir * 2, stream);
  hipMemsetAsync(hrl + (size_t)3072 * Ir, 0, (size_t)64 * Ir * 2, stream);

  router_kernel<<<Ttok, 64, 0, stream>>>(x, gate, cnt, tok, eidloc, wtk);
  offs_kernel<<<1, 64, 0, stream>>>(cnt, offs);
  split_x<<<Ttok / 4, 256, 0, stream>>>(x, xgh, xgl);
  gather_x<<<dim3(Ne, 8), 256, 0, stream>>>(x, tok, cnt, offs, xgh, xgl);

  gu_mfma<<<dim3(Ir / 64, Ne, 8), 256, 0, stream>>>(
      xgh, xgl, wg, sg, wu, su, cnt, offs, hrh, hrl, Ir);
  gu_mfma<<<dim3(I2d / 64, 1, 8), 256, 0, stream>>>(
      xgh, xgl, shwg, shsg, shwu, shsu, nullptr, nullptr, hsh, hsl, I2d);

  down_mfma<<<dim3(Hd / 64, Ne, 8), 256, 0, stream>>>(
      hrh, hrl, wd, sd, cnt, offs, yslot, Ir);
  down_mfma<<<dim3(Hd / 64, 1, 8), 256, 0, stream>>>(
      hsh, hsl, shwd, shsd, nullptr, nullptr, ysh, I2d);

  combine_kernel<<<Ttok, 256, 0, stream>>>(ysh, yslot, eidloc, wtk, offs, out);
}

// Round 3
// 524.483 us; speedup vs baseline: 3.8143x; 1.4686x over previous
//
#include <hip/hip_runtime.h>
#include <math.h>

#define Ttok 512
#define Hd   1024
#define Ne   64
#define Ir   512
#define I2d  1024
#define Kn   6
#define Ngrp 8
#define TGn  3
#define RPAD 7168

typedef __bf16 bf16x8 __attribute__((ext_vector_type(8)));
typedef float f32x4 __attribute__((ext_vector_type(4)));

__device__ __forceinline__ unsigned cvt_pk_bf16(float a, float b) {
  unsigned r;
  asm("v_cvt_pk_bf16_f32 %0, %1, %2" : "=v"(r) : "v"(a), "v"(b));
  return r;
}
__device__ __forceinline__ unsigned short f2bf_rne(float f) {
  unsigned u = __builtin_bit_cast(unsigned, f);
  return (unsigned short)((u + 0x7fffu + ((u >> 16) & 1u)) >> 16);
}
__device__ __forceinline__ float bf2f(unsigned short h) {
  unsigned u = ((unsigned)h) << 16;
  return __builtin_bit_cast(float, u);
}
__device__ __forceinline__ float wred64(float v) {
  #pragma unroll
  for (int m = 32; m >= 1; m >>= 1) v += __shfl_xor(v, m, 64);
  return v;
}

// ---------------- router: 1 block (4 waves) per token ----------------
__global__ __launch_bounds__(256) void router_kernel(
    const float* __restrict__ x, const float* __restrict__ gate,
    int* __restrict__ cnt, int* __restrict__ tok, float* __restrict__ wtl)
{
  const int t = blockIdx.x;
  const int lane = threadIdx.x & 63;
  const int wv = threadIdx.x >> 6;
  __shared__ float xs[Hd];
  __shared__ float sc[Ne];
  #pragma unroll
  for (int j = 0; j < 4; ++j) xs[threadIdx.x + 256 * j] = x[(size_t)t * Hd + threadIdx.x + 256 * j];
  __syncthreads();
  #pragma unroll 1
  for (int eo = 0; eo < 16; ++eo) {
    const int e = wv * 16 + eo;
    const float* gr = gate + (size_t)e * Hd;
    float p = 0.f;
    #pragma unroll
    for (int j = 0; j < 16; ++j) p = fmaf(gr[lane + 64 * j], xs[lane + 64 * j], p);
    p = wred64(p);
    if (lane == 0) sc[e] = 1.f / (1.f + expf(-p));
  }
  __syncthreads();
  if (threadIdx.x == 0) {
    float gs[Ngrp];
    #pragma unroll
    for (int g = 0; g < Ngrp; ++g) {
      float m = sc[g * 8];
      #pragma unroll
      for (int j = 1; j < 8; ++j) m = fmaxf(m, sc[g * 8 + j]);
      gs[g] = m;
    }
    unsigned gsel = 0;
    for (int r = 0; r < TGn; ++r) {
      int bg = -1; float bv = -3.4e38f;
      for (int g = 0; g < Ngrp; ++g)
        if (!((gsel >> g) & 1u) && gs[g] > bv) { bv = gs[g]; bg = g; }
      gsel |= 1u << bg;
    }
    int ide[Kn]; float val[Kn];
    unsigned long long taken = 0ull;
    for (int k = 0; k < Kn; ++k) {
      int be = -1; float bv = -3.4e38f;
      for (int e = 0; e < Ne; ++e) {
        if (!((gsel >> (e >> 3)) & 1u)) continue;
        if ((taken >> e) & 1ull) continue;
        if (sc[e] > bv) { bv = sc[e]; be = e; }
      }
      taken |= 1ull << be;
      ide[k] = be; val[k] = bv;
    }
    float s = 0.f;
    for (int k = 0; k < Kn; ++k) s += val[k];
    s += 1e-20f;
    for (int k = 0; k < Kn; ++k) {
      const float w = val[k] / s * 2.5f;
      const int e = ide[k];
      const int slot = atomicAdd(&cnt[e], 1);
      tok[e * Ttok + slot] = t;
      wtl[e * Ttok + slot] = w;
    }
  }
}

// 64-aligned padded cumsum
__global__ void offs_kernel(const int* __restrict__ cnt, int* __restrict__ offs) {
  if (threadIdx.x == 0 && blockIdx.x == 0) {
    int a = 0;
    for (int e = 0; e < Ne; ++e) { offs[e] = a; a += (cnt[e] + 63) & ~63; }
    offs[Ne] = a;
  }
}

// ---------------- x -> fragment-major bf16, identity rows [0,512) ----------------
// layout: chunk (g16 = row/16, kblk = k/32) at ((g16*32 + kblk)*64 + lane)*8,
// lane = (k%32)/8*16 + row%16, 8 consecutive k per lane.
__global__ __launch_bounds__(256) void split_x(
    const float* __restrict__ x, unsigned short* __restrict__ xg)
{
  const int b = blockIdx.x;            // rows [b*16, b*16+16)
  const int lane = threadIdx.x & 63;
  const int q = threadIdx.x >> 6;
  const int r = b * 16 + (lane & 15);
  const int ksub = (lane >> 4) * 8;
  #pragma unroll
  for (int kc = 0; kc < 8; ++kc) {
    const int kblk = q * 8 + kc;
    const float* px = x + (size_t)r * Hd + kblk * 32 + ksub;
    float4 v0 = *(const float4*)(px);
    float4 v1 = *(const float4*)(px + 4);
    uint4 o;
    o.x = cvt_pk_bf16(v0.x, v0.y);
    o.y = cvt_pk_bf16(v0.z, v0.w);
    o.z = cvt_pk_bf16(v1.x, v1.y);
    o.w = cvt_pk_bf16(v1.z, v1.w);
    *(uint4*)(xg + (((size_t)b * 32 + kblk) * 64 + lane) * 8) = o;
  }
}

// gathered rows [512, ...): per-expert compact (64-aligned) token rows
__global__ __launch_bounds__(256) void gather_x(
    const float* __restrict__ x, const int* __restrict__ tok,
    const int* __restrict__ cnt, const int* __restrict__ offs,
    unsigned short* __restrict__ xg)
{
  const int e = blockIdx.x;
  const int grp = blockIdx.y;
  const int n = cnt[e];
  if (grp * 16 >= n) return;
  const int lane = threadIdx.x & 63;
  const int q = threadIdx.x >> 6;
  const int s = grp * 16 + (lane & 15);
  const bool ok = s < n;
  const int t = ok ? tok[e * Ttok + s] : 0;
  const int g16 = ((Ttok + offs[e]) >> 4) + grp;
  const int ksub = (lane >> 4) * 8;
  #pragma unroll
  for (int kc = 0; kc < 8; ++kc) {
    const int kblk = q * 8 + kc;
    const float* px = x + (size_t)t * Hd + kblk * 32 + ksub;
    float4 v0 = *(const float4*)(px);
    float4 v1 = *(const float4*)(px + 4);
    uint4 o;
    o.x = cvt_pk_bf16(v0.x, v0.y);
    o.y = cvt_pk_bf16(v0.z, v0.w);
    o.z = cvt_pk_bf16(v1.x, v1.y);
    o.w = cvt_pk_bf16(v1.z, v1.w);
    if (ok) *(uint4*)(xg + (((size_t)g16 * 32 + kblk) * 64 + lane) * 8) = o;
  }
}

// ---------------- gate+up MFMA GEMM, coalesced staged weights ----------------
__global__ __launch_bounds__(256) void gu_mfma(
    const unsigned short* __restrict__ xg,
    const int* __restrict__ wgq, const float* __restrict__ sgs,
    const int* __restrict__ wuq, const float* __restrict__ sus,
    const int* __restrict__ cnt, const int* __restrict__ offs,
    unsigned short* __restrict__ hm, int Idim)
{
  const int e = blockIdx.y;
  const int n = cnt ? cnt[e] : Ttok;
  const int mbase = blockIdx.z * 64;
  if (mbase >= n) return;
  const int lane = threadIdx.x & 63;
  const int wv = threadIdx.x >> 6;
  const int iL = lane & 15;
  const int qk = lane >> 4;
  const int i0 = blockIdx.x * 64;
  const int g16x = ((offs ? (Ttok + offs[e]) : 0) + mbase) >> 4;
  const int g16h = ((offs ? offs[e] : 0) + mbase) >> 4;

  __shared__ char smem[65536];
  char* Ab0 = smem;
  char* Ab1 = smem + 16384;
  char* Bg = smem + 32768 + wv * 8192;
  char* Bu = Bg + 4096;

  const int sRows = Idim >> 7;
  const float* sG = sgs + ((size_t)e * sRows + (i0 >> 7)) * 8;
  const float* sU = sus + ((size_t)e * sRows + (i0 >> 7)) * 8;

  const int jrh = lane >> 5;
  const int kint = (lane & 31) * 4;
  const int* pG = wgq + ((size_t)e * Idim + i0 + wv * 16) * Hd;
  const int* pU = wuq + ((size_t)e * Idim + i0 + wv * 16) * Hd;

  int4 graw[8], uraw[8];
  f32x4 aG[4] = {{0,0,0,0},{0,0,0,0},{0,0,0,0},{0,0,0,0}};
  f32x4 aU[4] = {{0,0,0,0},{0,0,0,0},{0,0,0,0},{0,0,0,0}};

  auto loadB = [&](int kb) {
    #pragma unroll
    for (int j = 0; j < 8; ++j) {
      const size_t off = (size_t)(j * 2 + jrh) * Hd + kb * 128 + kint;
      graw[j] = *(const int4*)(pG + off);
      uraw[j] = *(const int4*)(pU + off);
    }
  };
  auto stageA = [&](int kb, char* dstbuf) {
    const unsigned short* src = xg + (((size_t)(g16x + wv) * 32 + kb * 4) * 64 + lane) * 8;
    char* dst = dstbuf + wv * 4096 + lane * 16;
    uint4 t0 = *(const uint4*)(src);
    uint4 t1 = *(const uint4*)(src + 512);
    uint4 t2 = *(const uint4*)(src + 1024);
    uint4 t3 = *(const uint4*)(src + 1536);
    *(uint4*)(dst) = t0;
    *(uint4*)(dst + 1024) = t1;
    *(uint4*)(dst + 2048) = t2;
    *(uint4*)(dst + 3072) = t3;
  };
  auto cvtWriteB = [&](int kb) {
    const float fg = sG[kb], fu = sU[kb];
    #pragma unroll
    for (int j = 0; j < 8; ++j) {
      const int r = j * 2 + jrh;
      const int w0 = r * 64 + ((kint >> 1) ^ ((r & 7) << 2));
      uint2 gv, uv;
      gv.x = cvt_pk_bf16((float)graw[j].x * fg, (float)graw[j].y * fg);
      gv.y = cvt_pk_bf16((float)graw[j].z * fg, (float)graw[j].w * fg);
      uv.x = cvt_pk_bf16((float)uraw[j].x * fu, (float)uraw[j].y * fu);
      uv.y = cvt_pk_bf16((float)uraw[j].z * fu, (float)uraw[j].w * fu);
      *(uint2*)(Bg + w0 * 4) = gv;
      *(uint2*)(Bu + w0 * 4) = uv;
    }
  };
  auto mfmaStep = [&](char* A) {
    #pragma unroll
    for (int ks = 0; ks < 4; ++ks) {
      const int bw = (iL * 64 + ((ks * 16 + qk * 4) ^ ((iL & 7) << 2))) * 4;
      bf16x8 bg = *(const bf16x8*)(Bg + bw);
      bf16x8 bu = *(const bf16x8*)(Bu + bw);
      #pragma unroll
      for (int mt = 0; mt < 4; ++mt) {
        bf16x8 a = *(const bf16x8*)(A + mt * 4096 + ks * 1024 + lane * 16);
        aG[mt] = __builtin_amdgcn_mfma_f32_16x16x32_bf16(a, bg, aG[mt], 0, 0, 0);
        aU[mt] = __builtin_amdgcn_mfma_f32_16x16x32_bf16(a, bu, aU[mt], 0, 0, 0);
      }
    }
  };

  stageA(0, Ab0);
  loadB(0);
  __syncthreads();
  #pragma unroll 1
  for (int kb = 0; kb < 8; ++kb) {
    cvtWriteB(kb);
    if (kb < 7) {
      stageA(kb + 1, (kb & 1) ? Ab0 : Ab1);
      loadB(kb + 1);
    }
    mfmaStep((kb & 1) ? Ab1 : Ab0);
    __syncthreads();
  }

  // epilogue: silu(g)*u -> LDS transpose -> fragment-major bf16 hm
  float* tile = (float*)(smem + 32768);
  #pragma unroll
  for (int mt = 0; mt < 4; ++mt) {
    #pragma unroll
    for (int j = 0; j < 4; ++j) {
      const float g = aG[mt][j], u = aU[mt][j];
      tile[(mt * 16 + qk * 4 + j) * 68 + wv * 16 + iL] = g / (1.f + expf(-g)) * u;
    }
  }
  __syncthreads();
  const int nkb = Idim >> 5;
  #pragma unroll
  for (int ib = 0; ib < 2; ++ib) {
    const float* srcp = tile + (wv * 16 + iL) * 68 + ib * 32 + qk * 8;
    uint4 ov;
    ov.x = cvt_pk_bf16(srcp[0], srcp[1]);
    ov.y = cvt_pk_bf16(srcp[2], srcp[3]);
    ov.z = cvt_pk_bf16(srcp[4], srcp[5]);
    ov.w = cvt_pk_bf16(srcp[6], srcp[7]);
    *(uint4*)(hm + (((size_t)(g16h + wv) * nkb + (i0 >> 5) + ib) * 64 + lane) * 8) = ov;
  }
}

// ---------------- down MFMA GEMM, fused scaled-atomic combine ----------------
__global__ __launch_bounds__(256) void down_mfma(
    const unsigned short* __restrict__ hm,
    const int* __restrict__ wdq, const float* __restrict__ sds,
    const int* __restrict__ cnt, const int* __restrict__ offs,
    const int* __restrict__ toks, const float* __restrict__ wtl,
    float* __restrict__ out, int Kd)
{
  const int e = blockIdx.y;
  const int n = cnt ? cnt[e] : Ttok;
  const int mbase = blockIdx.z * 64;
  if (mbase >= n) return;
  const int lane = threadIdx.x & 63;
  const int wv = threadIdx.x >> 6;
  const int hL = lane & 15;
  const int qk = lane >> 4;
  const int h0 = blockIdx.x * 64;
  const int g16a = ((offs ? offs[e] : 0) + mbase) >> 4;

  __shared__ char smem[49152];
  char* Ab0 = smem;
  char* Ab1 = smem + 16384;
  char* Bd = smem + 32768 + wv * 4096;

  const float* sD = sds + ((size_t)e * (Kd >> 7)) * 8 + (h0 >> 7);
  const int kLl = lane >> 2;
  const int hoff = (lane & 3) * 4;
  const int* pW = wdq + (size_t)e * Kd * Hd + h0 + wv * 16 + hoff;
  const int nka = Kd >> 5;

  int4 draw[8];
  f32x4 acc[4] = {{0,0,0,0},{0,0,0,0},{0,0,0,0},{0,0,0,0}};

  auto loadB = [&](int kb) {
    #pragma unroll
    for (int j = 0; j < 8; ++j)
      draw[j] = *(const int4*)(pW + (size_t)(kb * 128 + j * 16 + kLl) * Hd);
  };
  auto stageA = [&](int kb, char* dstbuf) {
    const unsigned short* src = hm + (((size_t)(g16a + wv) * nka + kb * 4) * 64 + lane) * 8;
    char* dst = dstbuf + wv * 4096 + lane * 16;
    uint4 t0 = *(const uint4*)(src);
    uint4 t1 = *(const uint4*)(src + 512);
    uint4 t2 = *(const uint4*)(src + 1024);
    uint4 t3 = *(const uint4*)(src + 1536);
    *(uint4*)(dst) = t0;
    *(uint4*)(dst + 1024) = t1;
    *(uint4*)(dst + 2048) = t2;
    *(uint4*)(dst + 3072) = t3;
  };
  auto cvtWriteB = [&](int kb) {
    const float fd = sD[kb * 8];
    #pragma unroll
    for (int j = 0; j < 8; ++j) {
      const int kL = j * 16 + kLl;
      const int* dv = &draw[j].x;
      #pragma unroll
      for (int c = 0; c < 4; ++c) {
        const int hl = hoff + c;
        const int addr = ((hl * 64 + ((kL >> 1) ^ ((hl & 7) << 2))) << 2) + (kL & 1) * 2;
        *(unsigned short*)(Bd + addr) = f2bf_rne((float)dv[c] * fd);
      }
    }
  };
  auto mfmaStep = [&](char* A) {
    #pragma unroll
    for (int ks = 0; ks < 4; ++ks) {
      bf16x8 b = *(const bf16x8*)(Bd + (hL * 64 + ((ks * 16 + qk * 4) ^ ((hL & 7) << 2))) * 4);
      #pragma unroll
      for (int mt = 0; mt < 4; ++mt) {
        bf16x8 a = *(const bf16x8*)(A + mt * 4096 + ks * 1024 + lane * 16);
        acc[mt] = __builtin_amdgcn_mfma_f32_16x16x32_bf16(a, b, acc[mt], 0, 0, 0);
      }
    }
  };

  const int nKb = Kd >> 7;
  stageA(0, Ab0);
  loadB(0);
  __syncthreads();
  #pragma unroll 1
  for (int kb = 0; kb < nKb; ++kb) {
    cvtWriteB(kb);
    if (kb + 1 < nKb) {
      stageA(kb + 1, (kb & 1) ? Ab0 : Ab1);
      loadB(kb + 1);
    }
    mfmaStep((kb & 1) ? Ab1 : Ab0);
    __syncthreads();
  }

  const int hW = h0 + wv * 16 + hL;
  #pragma unroll
  for (int mt = 0; mt < 4; ++mt) {
    #pragma unroll
    for (int j = 0; j < 4; ++j) {
      const int mr = mbase + mt * 16 + qk * 4 + j;
      if (mr < n) {
        const int t = toks ? toks[e * Ttok + mr] : mr;
        const float wt = wtl ? wtl[e * Ttok + mr] : 1.f;
        atomicAdd(&out[(size_t)t * Hd + hW], wt * acc[mt][j]);
      }
    }
  }
}

extern "C" void kernel_launch(void* const* d_in, const int* in_sizes, int n_in,
                              void* d_out, int out_size, void* d_ws, size_t ws_size,
                              hipStream_t stream)
{
  const float* x    = (const float*)d_in[0];
  const float* gate = (const float*)d_in[1];
  const int*   wg   = (const int*)d_in[2];
  const float* sg   = (const float*)d_in[3];
  const int*   wu   = (const int*)d_in[4];
  const float* su   = (const float*)d_in[5];
  const int*   wd   = (const int*)d_in[6];
  const float* sd   = (const float*)d_in[7];
  const int*   shwg = (const int*)d_in[8];
  const float* shsg = (const float*)d_in[9];
  const int*   shwu = (const int*)d_in[10];
  const float* shsu = (const float*)d_in[11];
  const int*   shwd = (const int*)d_in[12];
  const float* shsd = (const float*)d_in[13];
  float* out = (float*)d_out;

  char* p = (char*)d_ws;
  auto nxt = [&](size_t bytes) { char* r = p; p += (bytes + 255) & ~(size_t)255; return r; };
  int*   cnt  = (int*)nxt(Ne * 4);
  int*   offs = (int*)nxt((Ne + 1) * 4);
  int*   tok  = (int*)nxt((size_t)Ne * Ttok * 4);
  float* wtl  = (float*)nxt((size_t)Ne * Ttok * 4);
  unsigned short* xg = (unsigned short*)nxt((size_t)(Ttok + RPAD) * Hd * 2);
  unsigned short* hr = (unsigned short*)nxt((size_t)RPAD * Ir * 2);
  unsigned short* hs = (unsigned short*)nxt((size_t)Ttok * I2d * 2);

  hipMemsetAsync(cnt, 0, Ne * 4, stream);
  hipMemsetAsync(out, 0, (size_t)out_size * sizeof(float), stream);

  router_kernel<<<Ttok, 256, 0, stream>>>(x, gate, cnt, tok, wtl);
  offs_kernel<<<1, 64, 0, stream>>>(cnt, offs);
  split_x<<<Ttok / 16, 256, 0, stream>>>(x, xg);
  gather_x<<<dim3(Ne, Ttok / 16), 256, 0, stream>>>(x, tok, cnt, offs, xg);

  gu_mfma<<<dim3(Ir / 64, Ne, 8), 256, 0, stream>>>(
      xg, wg, sg, wu, su, cnt, offs, hr, Ir);
  gu_mfma<<<dim3(I2d / 64, 1, 8), 256, 0, stream>>>(
      xg, shwg, shsg, shwu, shsu, nullptr, nullptr, hs, I2d);

  down_mfma<<<dim3(Hd / 64, Ne, 8), 256, 0, stream>>>(
      hr, wd, sd, cnt, offs, tok, wtl, out, Ir);
  down_mfma<<<dim3(Hd / 64, 1, 8), 256, 0, stream>>>(
      hs, shwd, shsd, nullptr, nullptr, nullptr, nullptr, out, I2d);
}

// Round 4
// 516.127 us; speedup vs baseline: 3.8760x; 1.0162x over previous
//
#include <hip/hip_runtime.h>
#include <math.h>

#define Ttok 512
#define Hd   1024
#define Ne   64
#define Ir   512
#define I2d  1024
#define Kn   6
#define Ngrp 8
#define TGn  3
#define RPAD 7168

typedef __bf16 bf16x8 __attribute__((ext_vector_type(8)));
typedef float f32x4 __attribute__((ext_vector_type(4)));

__device__ __forceinline__ unsigned cvt_pk_bf16(float a, float b) {
  unsigned r;
  asm("v_cvt_pk_bf16_f32 %0, %1, %2" : "=v"(r) : "v"(a), "v"(b));
  return r;
}
__device__ __forceinline__ unsigned short f2bf_rne(float f) {
  unsigned u = __builtin_bit_cast(unsigned, f);
  return (unsigned short)((u + 0x7fffu + ((u >> 16) & 1u)) >> 16);
}
__device__ __forceinline__ float wred64(float v) {
  #pragma unroll
  for (int m = 32; m >= 1; m >>= 1) v += __shfl_xor(v, m, 64);
  return v;
}

// ---------------- router: 1 block (4 waves) per token ----------------
__global__ __launch_bounds__(256) void router_kernel(
    const float* __restrict__ x, const float* __restrict__ gate,
    int* __restrict__ cnt, int* __restrict__ tok, float* __restrict__ wtl)
{
  const int t = blockIdx.x;
  const int lane = threadIdx.x & 63;
  const int wv = threadIdx.x >> 6;
  __shared__ float xs[Hd];
  __shared__ float sc[Ne];
  #pragma unroll
  for (int j = 0; j < 4; ++j) xs[threadIdx.x + 256 * j] = x[(size_t)t * Hd + threadIdx.x + 256 * j];
  __syncthreads();
  #pragma unroll 1
  for (int eo = 0; eo < 16; ++eo) {
    const int e = wv * 16 + eo;
    const float* gr = gate + (size_t)e * Hd;
    float p = 0.f;
    #pragma unroll
    for (int j = 0; j < 16; ++j) p = fmaf(gr[lane + 64 * j], xs[lane + 64 * j], p);
    p = wred64(p);
    if (lane == 0) sc[e] = 1.f / (1.f + expf(-p));
  }
  __syncthreads();
  if (threadIdx.x == 0) {
    float gs[Ngrp];
    #pragma unroll
    for (int g = 0; g < Ngrp; ++g) {
      float m = sc[g * 8];
      #pragma unroll
      for (int j = 1; j < 8; ++j) m = fmaxf(m, sc[g * 8 + j]);
      gs[g] = m;
    }
    unsigned gsel = 0;
    for (int r = 0; r < TGn; ++r) {
      int bg = -1; float bv = -3.4e38f;
      for (int g = 0; g < Ngrp; ++g)
        if (!((gsel >> g) & 1u) && gs[g] > bv) { bv = gs[g]; bg = g; }
      gsel |= 1u << bg;
    }
    int ide[Kn]; float val[Kn];
    unsigned long long taken = 0ull;
    for (int k = 0; k < Kn; ++k) {
      int be = -1; float bv = -3.4e38f;
      for (int e = 0; e < Ne; ++e) {
        if (!((gsel >> (e >> 3)) & 1u)) continue;
        if ((taken >> e) & 1ull) continue;
        if (sc[e] > bv) { bv = sc[e]; be = e; }
      }
      taken |= 1ull << be;
      ide[k] = be; val[k] = bv;
    }
    float s = 0.f;
    for (int k = 0; k < Kn; ++k) s += val[k];
    s += 1e-20f;
    for (int k = 0; k < Kn; ++k) {
      const float w = val[k] / s * 2.5f;
      const int e = ide[k];
      const int slot = atomicAdd(&cnt[e], 1);
      tok[e * Ttok + slot] = t;
      wtl[e * Ttok + slot] = w;
    }
  }
}

// 64-aligned padded cumsum
__global__ void offs_kernel(const int* __restrict__ cnt, int* __restrict__ offs) {
  if (threadIdx.x == 0 && blockIdx.x == 0) {
    int a = 0;
    for (int e = 0; e < Ne; ++e) { offs[e] = a; a += (cnt[e] + 63) & ~63; }
    offs[Ne] = a;
  }
}

// ---------------- x -> fragment-major bf16, identity rows [0,512) ----------------
// chunk (g16 = row/16, kblk = k/32) at ((g16*32 + kblk)*64 + lane)*8 u16,
// lane = (k%32)/8*16 + row%16, 8 consecutive k per lane.
__global__ __launch_bounds__(256) void split_x(
    const float* __restrict__ x, unsigned short* __restrict__ xg)
{
  const int b = blockIdx.x;
  const int lane = threadIdx.x & 63;
  const int q = threadIdx.x >> 6;
  const int r = b * 16 + (lane & 15);
  const int ksub = (lane >> 4) * 8;
  #pragma unroll
  for (int kc = 0; kc < 8; ++kc) {
    const int kblk = q * 8 + kc;
    const float* px = x + (size_t)r * Hd + kblk * 32 + ksub;
    float4 v0 = *(const float4*)(px);
    float4 v1 = *(const float4*)(px + 4);
    uint4 o;
    o.x = cvt_pk_bf16(v0.x, v0.y);
    o.y = cvt_pk_bf16(v0.z, v0.w);
    o.z = cvt_pk_bf16(v1.x, v1.y);
    o.w = cvt_pk_bf16(v1.z, v1.w);
    *(uint4*)(xg + (((size_t)b * 32 + kblk) * 64 + lane) * 8) = o;
  }
}

// gathered rows [512, ...): per-expert compact (64-aligned) token rows
__global__ __launch_bounds__(256) void gather_x(
    const float* __restrict__ x, const int* __restrict__ tok,
    const int* __restrict__ cnt, const int* __restrict__ offs,
    unsigned short* __restrict__ xg)
{
  const int e = blockIdx.x;
  const int grp = blockIdx.y;
  const int n = cnt[e];
  if (grp * 16 >= n) return;
  const int lane = threadIdx.x & 63;
  const int q = threadIdx.x >> 6;
  const int s = grp * 16 + (lane & 15);
  const bool ok = s < n;
  const int t = ok ? tok[e * Ttok + s] : 0;
  const int g16 = ((Ttok + offs[e]) >> 4) + grp;
  const int ksub = (lane >> 4) * 8;
  #pragma unroll
  for (int kc = 0; kc < 8; ++kc) {
    const int kblk = q * 8 + kc;
    const float* px = x + (size_t)t * Hd + kblk * 32 + ksub;
    float4 v0 = *(const float4*)(px);
    float4 v1 = *(const float4*)(px + 4);
    uint4 o;
    o.x = cvt_pk_bf16(v0.x, v0.y);
    o.y = cvt_pk_bf16(v0.z, v0.w);
    o.z = cvt_pk_bf16(v1.x, v1.y);
    o.w = cvt_pk_bf16(v1.z, v1.w);
    if (ok) *(uint4*)(xg + (((size_t)g16 * 32 + kblk) * 64 + lane) * 8) = o;
  }
}

// ---------------- gate+up MFMA GEMM: barrier-free K-loop ----------------
// block 64M x 64N, wave = 64M x 16N strip; per-wave private B LDS; A from global.
__global__ __launch_bounds__(256, 2) void gu_mfma(
    const unsigned short* __restrict__ xg,
    const int* __restrict__ wgq, const float* __restrict__ sgs,
    const int* __restrict__ wuq, const float* __restrict__ sus,
    const int* __restrict__ cnt, const int* __restrict__ offs,
    unsigned short* __restrict__ hm, int Idim)
{
  const int e = blockIdx.y;
  const int n = cnt ? cnt[e] : Ttok;
  const int mbase = blockIdx.z * 64;
  if (mbase >= n) return;
  const int lane = threadIdx.x & 63;
  const int wv = threadIdx.x >> 6;
  const int iL = lane & 15;
  const int qk = lane >> 4;
  const int i0 = blockIdx.x * 64;
  const int g16x = ((offs ? (Ttok + offs[e]) : 0) + mbase) >> 4;
  const int g16h = ((offs ? offs[e] : 0) + mbase) >> 4;

  __shared__ char smem[32768];
  char* Bg = smem + wv * 8192;
  char* Bu = Bg + 4096;

  const int sRows = Idim >> 7;
  const float* sG = sgs + ((size_t)e * sRows + (i0 >> 7)) * 8;
  const float* sU = sus + ((size_t)e * sRows + (i0 >> 7)) * 8;

  const int jrh = lane >> 5;
  const int kint = (lane & 31) * 4;
  const int* pG = wgq + ((size_t)e * Idim + i0 + wv * 16) * Hd;
  const int* pU = wuq + ((size_t)e * Idim + i0 + wv * 16) * Hd;

  int4 graw[8], uraw[8];
  uint4 av[4][4];
  f32x4 aG[4] = {{0,0,0,0},{0,0,0,0},{0,0,0,0},{0,0,0,0}};
  f32x4 aU[4] = {{0,0,0,0},{0,0,0,0},{0,0,0,0},{0,0,0,0}};

  auto loadB = [&](int kb) {
    #pragma unroll
    for (int j = 0; j < 8; ++j) {
      const size_t off = (size_t)(j * 2 + jrh) * Hd + kb * 128 + kint;
      graw[j] = *(const int4*)(pG + off);
      uraw[j] = *(const int4*)(pU + off);
    }
  };
  auto loadA = [&](int kb) {
    #pragma unroll
    for (int mt = 0; mt < 4; ++mt)
      #pragma unroll
      for (int ks = 0; ks < 4; ++ks)
        av[mt][ks] = *(const uint4*)(xg + (((size_t)(g16x + mt) * 32 + kb * 4 + ks) * 64 + lane) * 8);
  };
  auto cvtWriteB = [&](int kb) {
    const float fg = sG[kb], fu = sU[kb];
    #pragma unroll
    for (int j = 0; j < 8; ++j) {
      const int r = j * 2 + jrh;
      const int w0 = r * 64 + ((kint >> 1) ^ ((r & 7) << 2));
      uint2 gv, uv;
      gv.x = cvt_pk_bf16((float)graw[j].x * fg, (float)graw[j].y * fg);
      gv.y = cvt_pk_bf16((float)graw[j].z * fg, (float)graw[j].w * fg);
      uv.x = cvt_pk_bf16((float)uraw[j].x * fu, (float)uraw[j].y * fu);
      uv.y = cvt_pk_bf16((float)uraw[j].z * fu, (float)uraw[j].w * fu);
      *(uint2*)(Bg + w0 * 4) = gv;
      *(uint2*)(Bu + w0 * 4) = uv;
    }
  };

  loadB(0);
  loadA(0);
  #pragma unroll 1
  for (int kb = 0; kb < 8; ++kb) {
    cvtWriteB(kb);
    if (kb < 7) loadB(kb + 1);
    #pragma unroll
    for (int ks = 0; ks < 4; ++ks) {
      const int bw = (iL * 64 + ((ks * 16 + qk * 4) ^ ((iL & 7) << 2))) * 4;
      bf16x8 bg = *(const bf16x8*)(Bg + bw);
      bf16x8 bu = *(const bf16x8*)(Bu + bw);
      #pragma unroll
      for (int mt = 0; mt < 4; ++mt) {
        bf16x8 a = __builtin_bit_cast(bf16x8, av[mt][ks]);
        aG[mt] = __builtin_amdgcn_mfma_f32_16x16x32_bf16(a, bg, aG[mt], 0, 0, 0);
        aU[mt] = __builtin_amdgcn_mfma_f32_16x16x32_bf16(a, bu, aU[mt], 0, 0, 0);
      }
    }
    if (kb < 7) loadA(kb + 1);
  }

  // epilogue: silu(g)*u -> LDS transpose -> fragment-major bf16 hm
  __syncthreads();
  float* tile = (float*)smem;
  #pragma unroll
  for (int mt = 0; mt < 4; ++mt) {
    #pragma unroll
    for (int j = 0; j < 4; ++j) {
      const float g = aG[mt][j], u = aU[mt][j];
      tile[(mt * 16 + qk * 4 + j) * 68 + wv * 16 + iL] = g / (1.f + expf(-g)) * u;
    }
  }
  __syncthreads();
  const int nkb = Idim >> 5;
  #pragma unroll
  for (int ib = 0; ib < 2; ++ib) {
    const float* srcp = tile + (wv * 16 + iL) * 68 + ib * 32 + qk * 8;
    uint4 ov;
    ov.x = cvt_pk_bf16(srcp[0], srcp[1]);
    ov.y = cvt_pk_bf16(srcp[2], srcp[3]);
    ov.z = cvt_pk_bf16(srcp[4], srcp[5]);
    ov.w = cvt_pk_bf16(srcp[6], srcp[7]);
    *(uint4*)(hm + (((size_t)(g16h + wv) * nkb + (i0 >> 5) + ib) * 64 + lane) * 8) = ov;
  }
}

// ---------------- down MFMA GEMM: barrier-free, fused scaled-atomic combine ----------------
// block 64M x 128N, wave = 64M x 32N strip (128B contiguous weight segments)
__global__ __launch_bounds__(256, 2) void down_mfma(
    const unsigned short* __restrict__ hm,
    const int* __restrict__ wdq, const float* __restrict__ sds,
    const int* __restrict__ cnt, const int* __restrict__ offs,
    const int* __restrict__ toks, const float* __restrict__ wtl,
    float* __restrict__ out, int Kd)
{
  const int e = blockIdx.y;
  const int n = cnt ? cnt[e] : Ttok;
  const int mbase = blockIdx.z * 64;
  if (mbase >= n) return;
  const int lane = threadIdx.x & 63;
  const int wv = threadIdx.x >> 6;
  const int iL = lane & 15;
  const int qk = lane >> 4;
  const int h0 = blockIdx.x * 128;
  const int hw = h0 + wv * 32;
  const int g16a = ((offs ? offs[e] : 0) + mbase) >> 4;
  const int nka = Kd >> 5;

  __shared__ char smem[32768];
  char* Bd = smem + wv * 8192;

  const float* sD = sds + (size_t)e * (Kd >> 7) * 8 + (h0 >> 7);
  const int kj = lane >> 3;
  const int hc = (lane & 7) * 4;
  const int* pW = wdq + (size_t)e * Kd * Hd + hw + hc;

  int4 draw[16];
  uint4 av[4][4];
  f32x4 acc[4][2] = {{{0,0,0,0},{0,0,0,0}},{{0,0,0,0},{0,0,0,0}},
                     {{0,0,0,0},{0,0,0,0}},{{0,0,0,0},{0,0,0,0}}};

  auto loadB = [&](int kb) {
    #pragma unroll
    for (int j = 0; j < 16; ++j)
      draw[j] = *(const int4*)(pW + (size_t)(kb * 128 + j * 8 + kj) * Hd);
  };
  auto loadA = [&](int kb) {
    #pragma unroll
    for (int mt = 0; mt < 4; ++mt)
      #pragma unroll
      for (int ks = 0; ks < 4; ++ks)
        av[mt][ks] = *(const uint4*)(hm + (((size_t)(g16a + mt) * nka + kb * 4 + ks) * 64 + lane) * 8);
  };
  auto cvtWriteB = [&](int kb) {
    const float fd = sD[kb * 8];
    #pragma unroll
    for (int j = 0; j < 16; ++j) {
      const int kL = j * 8 + kj;
      const int* dv = &draw[j].x;
      #pragma unroll
      for (int c = 0; c < 4; ++c) {
        const int hl = hc + c;
        const int addr = ((hl * 64 + ((kL >> 1) ^ ((hl & 7) << 2))) << 2) + (kL & 1) * 2;
        *(unsigned short*)(Bd + addr) = f2bf_rne((float)dv[c] * fd);
      }
    }
  };

  const int nKb = Kd >> 7;
  loadB(0);
  loadA(0);
  #pragma unroll 1
  for (int kb = 0; kb < nKb; ++kb) {
    cvtWriteB(kb);
    if (kb + 1 < nKb) loadB(kb + 1);
    #pragma unroll
    for (int ks = 0; ks < 4; ++ks) {
      #pragma unroll
      for (int ht = 0; ht < 2; ++ht) {
        const int row = ht * 16 + iL;
        bf16x8 b = *(const bf16x8*)(Bd + (row * 64 + ((ks * 16 + qk * 4) ^ ((row & 7) << 2))) * 4);
        #pragma unroll
        for (int mt = 0; mt < 4; ++mt) {
          bf16x8 a = __builtin_bit_cast(bf16x8, av[mt][ks]);
          acc[mt][ht] = __builtin_amdgcn_mfma_f32_16x16x32_bf16(a, b, acc[mt][ht], 0, 0, 0);
        }
      }
    }
    if (kb + 1 < nKb) loadA(kb + 1);
  }

  #pragma unroll
  for (int mt = 0; mt < 4; ++mt) {
    #pragma unroll
    for (int j = 0; j < 4; ++j) {
      const int mr = mbase + mt * 16 + qk * 4 + j;
      if (mr < n) {
        const int t = toks ? toks[e * Ttok + mr] : mr;
        const float wt = wtl ? wtl[e * Ttok + mr] : 1.f;
        atomicAdd(&out[(size_t)t * Hd + hw + iL], wt * acc[mt][0][j]);
        atomicAdd(&out[(size_t)t * Hd + hw + 16 + iL], wt * acc[mt][1][j]);
      }
    }
  }
}

extern "C" void kernel_launch(void* const* d_in, const int* in_sizes, int n_in,
                              void* d_out, int out_size, void* d_ws, size_t ws_size,
                              hipStream_t stream)
{
  const float* x    = (const float*)d_in[0];
  const float* gate = (const float*)d_in[1];
  const int*   wg   = (const int*)d_in[2];
  const float* sg   = (const float*)d_in[3];
  const int*   wu   = (const int*)d_in[4];
  const float* su   = (const float*)d_in[5];
  const int*   wd   = (const int*)d_in[6];
  const float* sd   = (const float*)d_in[7];
  const int*   shwg = (const int*)d_in[8];
  const float* shsg = (const float*)d_in[9];
  const int*   shwu = (const int*)d_in[10];
  const float* shsu = (const float*)d_in[11];
  const int*   shwd = (const int*)d_in[12];
  const float* shsd = (const float*)d_in[13];
  float* out = (float*)d_out;

  char* p = (char*)d_ws;
  auto nxt = [&](size_t bytes) { char* r = p; p += (bytes + 255) & ~(size_t)255; return r; };
  int*   cnt  = (int*)nxt(Ne * 4);
  int*   offs = (int*)nxt((Ne + 1) * 4);
  int*   tok  = (int*)nxt((size_t)Ne * Ttok * 4);
  float* wtl  = (float*)nxt((size_t)Ne * Ttok * 4);
  unsigned short* xg = (unsigned short*)nxt((size_t)(Ttok + RPAD) * Hd * 2);
  unsigned short* hr = (unsigned short*)nxt((size_t)RPAD * Ir * 2);
  unsigned short* hs = (unsigned short*)nxt((size_t)Ttok * I2d * 2);

  hipMemsetAsync(cnt, 0, Ne * 4, stream);
  hipMemsetAsync(out, 0, (size_t)out_size * sizeof(float), stream);

  router_kernel<<<Ttok, 256, 0, stream>>>(x, gate, cnt, tok, wtl);
  offs_kernel<<<1, 64, 0, stream>>>(cnt, offs);
  split_x<<<Ttok / 16, 256, 0, stream>>>(x, xg);
  gather_x<<<dim3(Ne, Ttok / 16), 256, 0, stream>>>(x, tok, cnt, offs, xg);

  gu_mfma<<<dim3(Ir / 64, Ne, 8), 256, 0, stream>>>(
      xg, wg, sg, wu, su, cnt, offs, hr, Ir);
  gu_mfma<<<dim3(I2d / 64, 1, 8), 256, 0, stream>>>(
      xg, shwg, shsg, shwu, shsu, nullptr, nullptr, hs, I2d);

  down_mfma<<<dim3(Hd / 128, Ne, 8), 256, 0, stream>>>(
      hr, wd, sd, cnt, offs, tok, wtl, out, Ir);
  down_mfma<<<dim3(Hd / 128, 1, 8), 256, 0, stream>>>(
      hs, shwd, shsd, nullptr, nullptr, nullptr, nullptr, out, I2d);
}